// Round 3
// baseline (11705.655 us; speedup 1.0000x reference)
//
#include <hip/hip_runtime.h>

// Problem constants (from reference): B=33 blocks, 8x8 blocks per image, S=8 images.
#define BLKSZ 33
#define NBB   1089   // 33*33
#define IMW   264    // 8*33

// ---------------------------------------------------------------------------
// blockify: img [S][264][264] -> X [N=64*S][1089], n = l*64 + h*8 + s, p=i*33+j
__global__ __launch_bounds__(256) void blockify_k(const float* __restrict__ in,
                                                  float* __restrict__ X, int S) {
  int gid = blockIdx.x * 256 + threadIdx.x;
  int total = S * 64 * NBB;
  if (gid >= total) return;
  int n = gid / NBB, p = gid - n * NBB;
  int l = n >> 6, h = (n >> 3) & 7, s = n & 7;
  int i = p / BLKSZ, j = p - i * BLKSZ;
  X[gid] = in[((size_t)s * IMW + h * BLKSZ + i) * IMW + l * BLKSZ + j];
}

// unblockify: X [N][1089] -> img [S][264][264]
__global__ __launch_bounds__(256) void unblockify_k(const float* __restrict__ X,
                                                    float* __restrict__ out, int S) {
  int gid = blockIdx.x * 256 + threadIdx.x;
  int total = S * IMW * IMW;
  if (gid >= total) return;
  int s = gid / (IMW * IMW);
  int rem = gid - s * IMW * IMW;
  int y = rem / IMW, x = rem - y * IMW;
  int h = y / BLKSZ, i = y - h * BLKSZ;
  int l = x / BLKSZ, j = x - l * BLKSZ;
  out[gid] = X[(size_t)(l * 64 + h * 8 + s) * NBB + i * BLKSZ + j];
}

// ---------------------------------------------------------------------------
// NT GEMM: C[i,j] = sum_k A[i,k]*B[j,k]   (both row-major, k contiguous)
// mode 0: C = dot
// mode 1: C = src1 - dot
// mode 2: C = step*dot + src1
// mode 3: C = src1 - step*dot + src2
__global__ __launch_bounds__(256) void gemm_nt(
    const float* __restrict__ Am, const float* __restrict__ Bm, float* __restrict__ Cm,
    int M, int N, int K, int lda, int ldb, int ldc,
    int mode, const float* __restrict__ step_ptr,
    const float* __restrict__ src1, const float* __restrict__ src2) {
  __shared__ float As[16][68];  // [k][row], padded
  __shared__ float Bs[16][68];
  int tid = threadIdx.x;
  int tx = tid & 15, ty = tid >> 4;
  int bi = blockIdx.y * 64, bj = blockIdx.x * 64;
  float acc[4][4] = {{0.f, 0.f, 0.f, 0.f}, {0.f, 0.f, 0.f, 0.f},
                     {0.f, 0.f, 0.f, 0.f}, {0.f, 0.f, 0.f, 0.f}};
  for (int k0 = 0; k0 < K; k0 += 16) {
#pragma unroll
    for (int t = 0; t < 4; ++t) {
      int e = tid + t * 256;
      int r = e >> 4, c = e & 15;
      int kk = k0 + c;
      int ar = bi + r;
      As[c][r] = (ar < M && kk < K) ? Am[(size_t)ar * lda + kk] : 0.f;
      int br = bj + r;
      Bs[c][r] = (br < N && kk < K) ? Bm[(size_t)br * ldb + kk] : 0.f;
    }
    __syncthreads();
#pragma unroll
    for (int kk = 0; kk < 16; ++kk) {
      float4 av = *(const float4*)&As[kk][ty * 4];
      float4 bv = *(const float4*)&Bs[kk][tx * 4];
      acc[0][0] += av.x * bv.x; acc[0][1] += av.x * bv.y; acc[0][2] += av.x * bv.z; acc[0][3] += av.x * bv.w;
      acc[1][0] += av.y * bv.x; acc[1][1] += av.y * bv.y; acc[1][2] += av.y * bv.z; acc[1][3] += av.y * bv.w;
      acc[2][0] += av.z * bv.x; acc[2][1] += av.z * bv.y; acc[2][2] += av.z * bv.z; acc[2][3] += av.z * bv.w;
      acc[3][0] += av.w * bv.x; acc[3][1] += av.w * bv.y; acc[3][2] += av.w * bv.z; acc[3][3] += av.w * bv.w;
    }
    __syncthreads();
  }
  float step = (mode >= 2) ? step_ptr[0] : 0.f;
#pragma unroll
  for (int r = 0; r < 4; ++r) {
    int i = bi + ty * 4 + r;
    if (i >= M) continue;
#pragma unroll
    for (int c = 0; c < 4; ++c) {
      int j = bj + tx * 4 + c;
      if (j >= N) continue;
      size_t idx = (size_t)i * ldc + j;
      float v = acc[r][c];
      float o;
      if (mode == 0)      o = v;
      else if (mode == 1) o = src1[idx] - v;
      else if (mode == 2) o = fmaf(step, v, src1[idx]);
      else                o = src1[idx] - step * v + src2[idx];
      Cm[idx] = o;
    }
  }
}

// ---------------------------------------------------------------------------
// Zero the 1-px halo border cells of two NHWC(32) fp32 buffers, geometry (nimg,H,W).
__global__ __launch_bounds__(256) void zero_borders_k(float* __restrict__ a,
                                                      float* __restrict__ b,
                                                      int nimg, int H, int W) {
  int Wp = W + 2, Hp = H + 2;
  int perim = 2 * Wp + 2 * H;
  int gid = blockIdx.x * 256 + threadIdx.x;
  int total = nimg * perim;
  if (gid >= total) return;
  int img = gid / perim, k = gid - img * perim;
  int row, col;
  if (k < Wp)            { row = 0;      col = k; }
  else if (k < 2 * Wp)   { row = Hp - 1; col = k - Wp; }
  else { int k2 = k - 2 * Wp; row = 1 + (k2 >> 1); col = (k2 & 1) ? (Wp - 1) : 0; }
  size_t off = ((size_t)(img * Hp + row) * Wp + col) * 32;  // 128B aligned
  float4 z = {0.f, 0.f, 0.f, 0.f};
  float4* pa = (float4*)(a + off);
  float4* pb = (float4*)(b + off);
#pragma unroll
  for (int q = 0; q < 8; ++q) { pa[q] = z; pb[q] = z; }
}

// ---------------------------------------------------------------------------
// conv1: planar fp32 [nimg][H][W] -> padded NHWC fp32 [nimg][H+2][W+2][32], relu(conv+bias)
__global__ __launch_bounds__(256) void conv1_k(const float* __restrict__ in,
                                               float* __restrict__ out,
                                               const float* __restrict__ w,   // [32][1][3][3]
                                               const float* __restrict__ b,
                                               int nimg, int H, int W) {
  __shared__ float wl[9][32];  // [tap][co]
  __shared__ float bl[32];
  int tid = threadIdx.x;
  for (int t = tid; t < 288; t += 256) {           // FIX: strided (288 > blockDim)
    int co = t / 9, tap = t - co * 9;
    wl[tap][co] = w[t];
  }
  if (tid < 32) bl[tid] = b[tid];
  __syncthreads();
  int gid = blockIdx.x * 256 + tid;
  if (gid >= nimg * H * W) return;
  int img = gid / (H * W);
  int rem = gid - img * H * W;
  int y = rem / W, x = rem - y * W;
  float acc[32];
#pragma unroll
  for (int c = 0; c < 32; ++c) acc[c] = bl[c];
  const float* ip = in + (size_t)img * H * W;
#pragma unroll
  for (int ty = 0; ty < 3; ++ty)
#pragma unroll
    for (int tx = 0; tx < 3; ++tx) {
      int yy = y + ty - 1, xx = x + tx - 1;
      if (yy >= 0 && yy < H && xx >= 0 && xx < W) {
        float v = ip[(size_t)yy * W + xx];
        const float* wp = &wl[ty * 3 + tx][0];
#pragma unroll
        for (int q = 0; q < 8; ++q) {
          float4 wv = *(const float4*)(wp + q * 4);
          acc[q * 4 + 0] += v * wv.x; acc[q * 4 + 1] += v * wv.y;
          acc[q * 4 + 2] += v * wv.z; acc[q * 4 + 3] += v * wv.w;
        }
      }
    }
  size_t ob = ((size_t)(img * (H + 2) + y + 1) * (W + 2) + x + 1) * 32;
#pragma unroll
  for (int q = 0; q < 8; ++q) {
    float4 f;
    f.x = fmaxf(acc[4 * q + 0], 0.f);
    f.y = fmaxf(acc[4 * q + 1], 0.f);
    f.z = fmaxf(acc[4 * q + 2], 0.f);
    f.w = fmaxf(acc[4 * q + 3], 0.f);
    *(float4*)(out + ob + 4 * q) = f;
  }
}

// ---------------------------------------------------------------------------
// conv2: padded NHWC fp32 -> padded NHWC fp32, 32->32, relu(conv+bias).
// Thread computes 4 consecutive x pixels x 16 output channels.
__global__ __launch_bounds__(256) void conv2_k(const float* __restrict__ in,
                                               float* __restrict__ out,
                                               const float* __restrict__ w,   // [32][32][3][3]
                                               const float* __restrict__ b,
                                               int nimg, int H, int W) {
  __shared__ float wl[9][32][32];  // [tap][ci][co]  36.9 KB
  __shared__ float bl[32];
  int tid = threadIdx.x;
  for (int t = tid; t < 9216; t += 256) {
    int co = t / 288;
    int r = t - co * 288;
    int ci = r / 9, tap = r - ci * 9;
    wl[tap][ci][co] = w[t];
  }
  if (tid < 32) bl[tid] = b[tid];
  __syncthreads();
  int gW = (W + 3) >> 2;
  int total = nimg * H * gW * 2;
  int gid = blockIdx.x * 256 + tid;
  if (gid >= total) return;
  int coh = gid & 1;
  int g = gid >> 1;
  int gx = g % gW;
  int t2 = g / gW;
  int y = t2 % H;
  int img = t2 / H;
  int x = gx * 4;
  int Wp = W + 2;
  float acc[4][16];
#pragma unroll
  for (int p = 0; p < 4; ++p)
#pragma unroll
    for (int c = 0; c < 16; ++c) acc[p][c] = bl[coh * 16 + c];
  int ncols = Wp - x; if (ncols > 6) ncols = 6;
  size_t base = (size_t)(img * (H + 2)) * Wp;
#pragma unroll 1
  for (int ci2 = 0; ci2 < 16; ++ci2) {
    float2 vin[3][6];
#pragma unroll
    for (int r = 0; r < 3; ++r) {
      const float* rp = in + (base + (size_t)(y + r) * Wp + x) * 32 + ci2 * 2;
#pragma unroll
      for (int c = 0; c < 6; ++c) {
        if (c < ncols) vin[r][c] = *(const float2*)(rp + c * 32);
        else { vin[r][c].x = 0.f; vin[r][c].y = 0.f; }
      }
    }
#pragma unroll
    for (int ty = 0; ty < 3; ++ty)
#pragma unroll
      for (int tx = 0; tx < 3; ++tx) {
        int tap = ty * 3 + tx;
        const float* w0 = &wl[tap][2 * ci2][coh * 16];
        const float* w1 = &wl[tap][2 * ci2 + 1][coh * 16];
        float wA[16], wB[16];
#pragma unroll
        for (int q = 0; q < 4; ++q) {
          float4 t0 = *(const float4*)(w0 + 4 * q);
          wA[4 * q + 0] = t0.x; wA[4 * q + 1] = t0.y; wA[4 * q + 2] = t0.z; wA[4 * q + 3] = t0.w;
          float4 t1 = *(const float4*)(w1 + 4 * q);
          wB[4 * q + 0] = t1.x; wB[4 * q + 1] = t1.y; wB[4 * q + 2] = t1.z; wB[4 * q + 3] = t1.w;
        }
#pragma unroll
        for (int p = 0; p < 4; ++p) {
          float vlo = vin[ty][p + tx].x;
          float vhi = vin[ty][p + tx].y;
#pragma unroll
          for (int c = 0; c < 16; ++c) {
            acc[p][c] += vlo * wA[c];
            acc[p][c] += vhi * wB[c];
          }
        }
      }
  }
#pragma unroll
  for (int p = 0; p < 4; ++p) {
    if (x + p < W) {
      float* op = out + (base + (size_t)(y + 1) * Wp + (x + p + 1)) * 32 + coh * 16;
#pragma unroll
      for (int q = 0; q < 4; ++q) {
        float4 f;
        f.x = fmaxf(acc[p][4 * q + 0], 0.f);
        f.y = fmaxf(acc[p][4 * q + 1], 0.f);
        f.z = fmaxf(acc[p][4 * q + 2], 0.f);
        f.w = fmaxf(acc[p][4 * q + 3], 0.f);
        *(float4*)(op + 4 * q) = f;
      }
    }
  }
}

// ---------------------------------------------------------------------------
// conv4: padded NHWC fp32 -> planar fp32, 32->1, no bias, no relu.
// sub: out = src - conv   (deblock in-place subtract), else out = conv.
__global__ __launch_bounds__(256) void conv4_k(const float* __restrict__ in,
                                               float* __restrict__ out,
                                               const float* __restrict__ w,   // [1][32][3][3]
                                               const float* __restrict__ src,
                                               int nimg, int H, int W, int sub) {
  __shared__ float wl[9][32];  // [tap][ci]
  int tid = threadIdx.x;
  for (int t = tid; t < 288; t += 256) {           // FIX: strided (288 > blockDim)
    int ci = t / 9, tap = t - ci * 9;
    wl[tap][ci] = w[t];
  }
  __syncthreads();
  int gid = blockIdx.x * 256 + tid;
  if (gid >= nimg * H * W) return;
  int img = gid / (H * W);
  int rem = gid - img * H * W;
  int y = rem / W, x = rem - y * W;
  int Wp = W + 2;
  float acc = 0.f;
#pragma unroll
  for (int ty = 0; ty < 3; ++ty)
#pragma unroll
    for (int tx = 0; tx < 3; ++tx) {
      const float2* ip = (const float2*)(in + ((size_t)(img * (H + 2) + y + ty) * Wp + x + tx) * 32);
      const float* wp = &wl[ty * 3 + tx][0];
#pragma unroll
      for (int c2 = 0; c2 < 16; ++c2) {
        float2 v = ip[c2];
        acc += v.x * wp[2 * c2];
        acc += v.y * wp[2 * c2 + 1];
      }
    }
  out[gid] = sub ? (src[gid] - acc) : acc;
}

// ---------------------------------------------------------------------------
static inline int cdiv(int a, int b) { return (a + b - 1) / b; }

extern "C" void kernel_launch(void* const* d_in, const int* in_sizes, int n_in,
                              void* d_out, int out_size, void* d_ws, size_t ws_size,
                              hipStream_t stream) {
  const float* d_inputs = (const float*)d_in[0];
  const float* d_A      = (const float*)d_in[1];
  const float* d_Q      = (const float*)d_in[2];   // Q == A^T, [1089][272] row-major
  const float* d_steps  = (const float*)d_in[3];
  const float* den_w1 = (const float*)d_in[4];
  const float* den_b1 = (const float*)d_in[5];
  const float* den_w2 = (const float*)d_in[6];
  const float* den_b2 = (const float*)d_in[7];
  const float* den_w3 = (const float*)d_in[8];
  const float* den_b3 = (const float*)d_in[9];
  const float* den_w4 = (const float*)d_in[10];
  const float* deb_w1 = (const float*)d_in[11];
  const float* deb_b1 = (const float*)d_in[12];
  const float* deb_w2 = (const float*)d_in[13];
  const float* deb_b2 = (const float*)d_in[14];
  const float* deb_w3 = (const float*)d_in[15];
  const float* deb_b3 = (const float*)d_in[16];
  const float* deb_w4 = (const float*)d_in[17];

  int layers = in_sizes[3];                 // 5
  int M      = in_sizes[1] / NBB;           // 272
  int S      = in_sizes[0] / (IMW * IMW);   // 8
  int N      = 64 * S;                      // 512 block-columns

  // ---- workspace layout (all regions 128B aligned) ----
  float* ws    = (float*)d_ws;
  float* AtA   = ws;                         // 1089*1089 -> padded 1185936
  float* X     = AtA + 1185936;
  float* y2    = X + (size_t)N * NBB;        // [N][M]
  float* r2    = y2 + (size_t)N * M;
  float* z     = r2 + (size_t)N * M;         // [N][1089]
  float* noise = z + (size_t)N * NBB;
  float* img   = noise + (size_t)N * NBB;    // [S][264][264]
  float* buf1  = img + (size_t)S * IMW * IMW;
  size_t bufElems = (size_t)N * 35 * 35 * 32;  // >= S*266*266*32
  float* buf2  = buf1 + bufElems;

  dim3 blk(256);

  // ---- setup ----
  // blockify input into z (temp)
  blockify_k<<<cdiv(N * NBB, 256), blk, 0, stream>>>(d_inputs, z, S);
  // AtA = NT(Q, Q)   [1089][1089], K = M
  gemm_nt<<<dim3(cdiv(NBB, 64), cdiv(NBB, 64)), blk, 0, stream>>>(
      d_Q, d_Q, AtA, NBB, NBB, M, M, M, NBB, 0, nullptr, nullptr, nullptr);
  // y2 = NT(z, A)   [N][M], K = 1089
  gemm_nt<<<dim3(cdiv(M, 64), cdiv(N, 64)), blk, 0, stream>>>(
      z, d_A, y2, N, M, NBB, NBB, NBB, M, 0, nullptr, nullptr, nullptr);
  // X = NT(y2, Q)   [N][1089], K = M
  gemm_nt<<<dim3(cdiv(NBB, 64), cdiv(N, 64)), blk, 0, stream>>>(
      y2, d_Q, X, N, NBB, M, M, M, NBB, 0, nullptr, nullptr, nullptr);

  for (int n = 0; n < layers; ++n) {
    const float* stepp = d_steps + n;
    // r2 = y2 - NT(X, A)
    gemm_nt<<<dim3(cdiv(M, 64), cdiv(N, 64)), blk, 0, stream>>>(
        X, d_A, r2, N, M, NBB, NBB, NBB, M, 1, nullptr, y2, nullptr);
    // z = step*NT(r2, Q) + X
    gemm_nt<<<dim3(cdiv(NBB, 64), cdiv(N, 64)), blk, 0, stream>>>(
        r2, d_Q, z, N, NBB, M, M, M, NBB, 2, stepp, X, nullptr);

    // ---- denoise CNN on X (512 images of 33x33) ----
    zero_borders_k<<<cdiv(N * (2 * 35 + 2 * 33), 256), blk, 0, stream>>>(buf1, buf2, N, BLKSZ, BLKSZ);
    conv1_k<<<cdiv(N * NBB, 256), blk, 0, stream>>>(X, buf1, den_w1 + n * 288, den_b1 + n * 32, N, BLKSZ, BLKSZ);
    conv2_k<<<cdiv(N * BLKSZ * 9 * 2, 256), blk, 0, stream>>>(buf1, buf2, den_w2 + n * 9216, den_b2 + n * 32, N, BLKSZ, BLKSZ);
    conv2_k<<<cdiv(N * BLKSZ * 9 * 2, 256), blk, 0, stream>>>(buf2, buf1, den_w3 + n * 9216, den_b3 + n * 32, N, BLKSZ, BLKSZ);
    conv4_k<<<cdiv(N * NBB, 256), blk, 0, stream>>>(buf1, noise, den_w4 + n * 288, nullptr, N, BLKSZ, BLKSZ, 0);

    // X = z - step*NT(noise, AtA) + noise
    gemm_nt<<<dim3(cdiv(NBB, 64), cdiv(N, 64)), blk, 0, stream>>>(
        noise, AtA, X, N, NBB, NBB, NBB, NBB, NBB, 3, stepp, z, noise);

    // img = unblockify(X)
    unblockify_k<<<cdiv(S * IMW * IMW, 256), blk, 0, stream>>>(X, img, S);

    // ---- deblock CNN on img (S images of 264x264) ----
    zero_borders_k<<<cdiv(S * (2 * 266 + 2 * 264), 256), blk, 0, stream>>>(buf1, buf2, S, IMW, IMW);
    conv1_k<<<cdiv(S * IMW * IMW, 256), blk, 0, stream>>>(img, buf1, deb_w1 + n * 288, deb_b1 + n * 32, S, IMW, IMW);
    conv2_k<<<cdiv(S * IMW * 66 * 2, 256), blk, 0, stream>>>(buf1, buf2, deb_w2 + n * 9216, deb_b2 + n * 32, S, IMW, IMW);
    conv2_k<<<cdiv(S * IMW * 66 * 2, 256), blk, 0, stream>>>(buf2, buf1, deb_w3 + n * 9216, deb_b3 + n * 32, S, IMW, IMW);
    conv4_k<<<cdiv(S * IMW * IMW, 256), blk, 0, stream>>>(buf1, img, deb_w4 + n * 288, img, S, IMW, IMW, 1);

    // X = blockify(img)
    blockify_k<<<cdiv(N * NBB, 256), blk, 0, stream>>>(img, X, S);
  }

  // output = unblockify(X)
  unblockify_k<<<cdiv(S * IMW * IMW, 256), blk, 0, stream>>>(X, (float*)d_out, S);
}

// Round 5
// 4099.686 us; speedup vs baseline: 2.8553x; 2.8553x over previous
//
#include <hip/hip_runtime.h>
#include <hip/hip_fp16.h>

// Problem constants (from reference): B=33 blocks, 8x8 blocks per image, S=8 images.
#define BLKSZ 33
#define NBB   1089   // 33*33
#define IMW   264    // 8*33

typedef _Float16 f16x8 __attribute__((ext_vector_type(8)));
typedef float f32x4 __attribute__((ext_vector_type(4)));

// ---------------------------------------------------------------------------
// blockify: img [S][264][264] -> X [N=64*S][1089], n = l*64 + h*8 + s, p=i*33+j
__global__ __launch_bounds__(256) void blockify_k(const float* __restrict__ in,
                                                  float* __restrict__ X, int S) {
  int gid = blockIdx.x * 256 + threadIdx.x;
  int total = S * 64 * NBB;
  if (gid >= total) return;
  int n = gid / NBB, p = gid - n * NBB;
  int l = n >> 6, h = (n >> 3) & 7, s = n & 7;
  int i = p / BLKSZ, j = p - i * BLKSZ;
  X[gid] = in[((size_t)s * IMW + h * BLKSZ + i) * IMW + l * BLKSZ + j];
}

// unblockify: X [N][1089] -> img [S][264][264]
__global__ __launch_bounds__(256) void unblockify_k(const float* __restrict__ X,
                                                    float* __restrict__ out, int S) {
  int gid = blockIdx.x * 256 + threadIdx.x;
  int total = S * IMW * IMW;
  if (gid >= total) return;
  int s = gid / (IMW * IMW);
  int rem = gid - s * IMW * IMW;
  int y = rem / IMW, x = rem - y * IMW;
  int h = y / BLKSZ, i = y - h * BLKSZ;
  int l = x / BLKSZ, j = x - l * BLKSZ;
  out[gid] = X[(size_t)(l * 64 + h * 8 + s) * NBB + i * BLKSZ + j];
}

// ---------------------------------------------------------------------------
// NT GEMM: C[i,j] = sum_k A[i,k]*B[j,k]   (both row-major, k contiguous)
// mode 0: C = dot ; 1: C = src1 - dot ; 2: C = step*dot + src1 ; 3: C = src1 - step*dot + src2
__global__ __launch_bounds__(256) void gemm_nt(
    const float* __restrict__ Am, const float* __restrict__ Bm, float* __restrict__ Cm,
    int M, int N, int K, int lda, int ldb, int ldc,
    int mode, const float* __restrict__ step_ptr,
    const float* __restrict__ src1, const float* __restrict__ src2) {
  __shared__ float As[16][68];
  __shared__ float Bs[16][68];
  int tid = threadIdx.x;
  int tx = tid & 15, ty = tid >> 4;
  int bi = blockIdx.y * 64, bj = blockIdx.x * 64;
  float acc[4][4] = {{0.f, 0.f, 0.f, 0.f}, {0.f, 0.f, 0.f, 0.f},
                     {0.f, 0.f, 0.f, 0.f}, {0.f, 0.f, 0.f, 0.f}};
  for (int k0 = 0; k0 < K; k0 += 16) {
#pragma unroll
    for (int t = 0; t < 4; ++t) {
      int e = tid + t * 256;
      int r = e >> 4, c = e & 15;
      int kk = k0 + c;
      int ar = bi + r;
      As[c][r] = (ar < M && kk < K) ? Am[(size_t)ar * lda + kk] : 0.f;
      int br = bj + r;
      Bs[c][r] = (br < N && kk < K) ? Bm[(size_t)br * ldb + kk] : 0.f;
    }
    __syncthreads();
#pragma unroll
    for (int kk = 0; kk < 16; ++kk) {
      float4 av = *(const float4*)&As[kk][ty * 4];
      float4 bv = *(const float4*)&Bs[kk][tx * 4];
      acc[0][0] += av.x * bv.x; acc[0][1] += av.x * bv.y; acc[0][2] += av.x * bv.z; acc[0][3] += av.x * bv.w;
      acc[1][0] += av.y * bv.x; acc[1][1] += av.y * bv.y; acc[1][2] += av.y * bv.z; acc[1][3] += av.y * bv.w;
      acc[2][0] += av.z * bv.x; acc[2][1] += av.z * bv.y; acc[2][2] += av.z * bv.z; acc[2][3] += av.z * bv.w;
      acc[3][0] += av.w * bv.x; acc[3][1] += av.w * bv.y; acc[3][2] += av.w * bv.z; acc[3][3] += av.w * bv.w;
    }
    __syncthreads();
  }
  float step = (mode >= 2) ? step_ptr[0] : 0.f;
#pragma unroll
  for (int r = 0; r < 4; ++r) {
    int i = bi + ty * 4 + r;
    if (i >= M) continue;
#pragma unroll
    for (int c = 0; c < 4; ++c) {
      int j = bj + tx * 4 + c;
      if (j >= N) continue;
      size_t idx = (size_t)i * ldc + j;
      float v = acc[r][c];
      float o;
      if (mode == 0)      o = v;
      else if (mode == 1) o = src1[idx] - v;
      else if (mode == 2) o = fmaf(step, v, src1[idx]);
      else                o = src1[idx] - step * v + src2[idx];
      Cm[idx] = o;
    }
  }
}

// ---------------------------------------------------------------------------
// Pack conv2-type weights fp32 [co][ci][3][3] -> fp16 [slot][tap][co][ci].
// slot = layer*4 + {0:den_w2, 1:den_w3, 2:deb_w2, 3:deb_w3}
__global__ __launch_bounds__(256) void pack_w_k(const float* __restrict__ w0,
                                                const float* __restrict__ w1,
                                                const float* __restrict__ w2,
                                                const float* __restrict__ w3,
                                                __half* __restrict__ wp, int layers) {
  int gid = blockIdx.x * 256 + threadIdx.x;
  int total = layers * 4 * 9216;
  if (gid >= total) return;
  int slot = gid / 9216, r = gid - slot * 9216;
  int n = slot >> 2, which = slot & 3;
  int tap = r / 1024, r2 = r - tap * 1024;
  int co = r2 >> 5, ci = r2 & 31;
  const float* src = (which == 0) ? w0 : (which == 1) ? w1 : (which == 2) ? w2 : w3;
  wp[gid] = __float2half(src[n * 9216 + (co * 32 + ci) * 9 + tap]);
}

// ---------------------------------------------------------------------------
// Zero the 1-px halo border cells of two NHWC(32) fp16 buffers, geometry (nimg,H,W).
__global__ __launch_bounds__(256) void zero_borders_k(__half* __restrict__ a,
                                                      __half* __restrict__ b,
                                                      int nimg, int H, int W) {
  int Wp = W + 2, Hp = H + 2;
  int perim = 2 * Wp + 2 * H;
  int gid = blockIdx.x * 256 + threadIdx.x;
  int total = nimg * perim;
  if (gid >= total) return;
  int img = gid / perim, k = gid - img * perim;
  int row, col;
  if (k < Wp)            { row = 0;      col = k; }
  else if (k < 2 * Wp)   { row = Hp - 1; col = k - Wp; }
  else { int k2 = k - 2 * Wp; row = 1 + (k2 >> 1); col = (k2 & 1) ? (Wp - 1) : 0; }
  size_t off = ((size_t)(img * Hp + row) * Wp + col) * 32;  // halves; 64B aligned
  float4 z = {0.f, 0.f, 0.f, 0.f};
  float4* pa = (float4*)(a + off);
  float4* pb = (float4*)(b + off);
#pragma unroll
  for (int q = 0; q < 4; ++q) { pa[q] = z; pb[q] = z; }
}

// ---------------------------------------------------------------------------
// conv1: planar fp32 [nimg][H][W] -> padded NHWC fp16 [nimg][H+2][W+2][32], relu(conv+bias)
__global__ __launch_bounds__(256) void conv1_k(const float* __restrict__ in,
                                               __half* __restrict__ out,
                                               const float* __restrict__ w,   // [32][1][3][3]
                                               const float* __restrict__ b,
                                               int nimg, int H, int W) {
  __shared__ float wl[9][32];  // [tap][co]
  __shared__ float bl[32];
  int tid = threadIdx.x;
  for (int t = tid; t < 288; t += 256) {
    int co = t / 9, tap = t - co * 9;
    wl[tap][co] = w[t];
  }
  if (tid < 32) bl[tid] = b[tid];
  __syncthreads();
  int gid = blockIdx.x * 256 + tid;
  if (gid >= nimg * H * W) return;
  int img = gid / (H * W);
  int rem = gid - img * H * W;
  int y = rem / W, x = rem - y * W;
  float acc[32];
#pragma unroll
  for (int c = 0; c < 32; ++c) acc[c] = bl[c];
  const float* ip = in + (size_t)img * H * W;
#pragma unroll
  for (int ty = 0; ty < 3; ++ty)
#pragma unroll
    for (int tx = 0; tx < 3; ++tx) {
      int yy = y + ty - 1, xx = x + tx - 1;
      if (yy >= 0 && yy < H && xx >= 0 && xx < W) {
        float v = ip[(size_t)yy * W + xx];
        const float* wp = &wl[ty * 3 + tx][0];
#pragma unroll
        for (int q = 0; q < 8; ++q) {
          float4 wv = *(const float4*)(wp + q * 4);
          acc[q * 4 + 0] += v * wv.x; acc[q * 4 + 1] += v * wv.y;
          acc[q * 4 + 2] += v * wv.z; acc[q * 4 + 3] += v * wv.w;
        }
      }
    }
  size_t ob = ((size_t)(img * (H + 2) + y + 1) * (W + 2) + x + 1) * 32;
  __half2* op = (__half2*)(out + ob);
#pragma unroll
  for (int c2 = 0; c2 < 16; ++c2)
    op[c2] = __floats2half2_rn(fmaxf(acc[2 * c2], 0.f), fmaxf(acc[2 * c2 + 1], 0.f));
}

// ---------------------------------------------------------------------------
// conv2 via MFMA fp16 implicit GEMM: padded NHWC fp16 -> padded NHWC fp16,
// 32->32, relu(conv+bias). One wave = 16 px x 16 co tile; loops x-tiles of a row.
// A[m][k]: m = out-pixel in tile (lane&15), k = ci (lane>>4)*8+j  -> NHWC 16B load
// B[k][n]: n = co (lane&15), k = ci                               -> packed weights
// C[m][n]: n = co (lane&15), m = (lane>>4)*4 + r
__global__ __launch_bounds__(256) void conv2_mfma_k(const __half* __restrict__ in,
                                                    __half* __restrict__ out,
                                                    const __half* __restrict__ wp,  // [9][32][32]
                                                    const float* __restrict__ bias,
                                                    int nimg, int H, int W) {
  int wid = blockIdx.x * 4 + (threadIdx.x >> 6);
  int total = nimg * H * 2;
  if (wid >= total) return;
  int lane = threadIdx.x & 63;
  int m16 = lane & 15, kg = lane >> 4;
  int cohalf = wid & 1;
  int t = wid >> 1;
  int y = t % H;
  int img = t / H;
  int Wp = W + 2, Hp = H + 2;
  // B fragments: 9 taps, held in registers for the whole row
  f16x8 bfr[9];
#pragma unroll
  for (int tap = 0; tap < 9; ++tap)
    bfr[tap] = *(const f16x8*)(wp + ((tap * 32 + cohalf * 16 + m16) * 32 + kg * 8));
  float bv = bias[cohalf * 16 + m16];
  int ntx = (W + 15) >> 4;
  size_t ibase = (size_t)img * Hp * Wp;
  for (int xt = 0; xt < ntx; ++xt) {
    int x0 = xt << 4;
    f32x4 acc0 = {0.f, 0.f, 0.f, 0.f};
    f32x4 acc1 = {0.f, 0.f, 0.f, 0.f};
#pragma unroll
    for (int ty = 0; ty < 3; ++ty) {
      size_t rbase = ibase + (size_t)(y + ty) * Wp;
#pragma unroll
      for (int tx = 0; tx < 3; ++tx) {
        int col = x0 + m16 + tx;               // padded col of input pixel
        if (col > W + 1) col = W + 1;          // clamp (rows with <16 valid px)
        f16x8 afr = *(const f16x8*)(in + (rbase + col) * 32 + kg * 8);
        if (((ty * 3 + tx) & 1) == 0)
          acc0 = __builtin_amdgcn_mfma_f32_16x16x32_f16(afr, bfr[ty * 3 + tx], acc0, 0, 0, 0);
        else
          acc1 = __builtin_amdgcn_mfma_f32_16x16x32_f16(afr, bfr[ty * 3 + tx], acc1, 0, 0, 0);
      }
    }
#pragma unroll
    for (int r = 0; r < 4; ++r) {
      int p = kg * 4 + r;        // pixel within tile
      int xo = x0 + p;
      if (xo < W) {
        float v = fmaxf(acc0[r] + acc1[r] + bv, 0.f);
        out[(ibase + (size_t)(y + 1) * Wp + (xo + 1)) * 32 + cohalf * 16 + m16] = __float2half(v);
      }
    }
  }
}

// ---------------------------------------------------------------------------
// conv4: padded NHWC fp16 -> planar fp32, 32->1, no bias, no relu.
// sub: out = src - conv (deblock subtract), else out = conv.
__global__ __launch_bounds__(256) void conv4_k(const __half* __restrict__ in,
                                               float* __restrict__ out,
                                               const float* __restrict__ w,   // [1][32][3][3]
                                               const float* __restrict__ src,
                                               int nimg, int H, int W, int sub) {
  __shared__ float wl[9][32];  // [tap][ci]
  int tid = threadIdx.x;
  for (int t = tid; t < 288; t += 256) {
    int ci = t / 9, tap = t - ci * 9;
    wl[tap][ci] = w[t];
  }
  __syncthreads();
  int gid = blockIdx.x * 256 + tid;
  if (gid >= nimg * H * W) return;
  int img = gid / (H * W);
  int rem = gid - img * H * W;
  int y = rem / W, x = rem - y * W;
  int Wp = W + 2;
  float acc = 0.f;
#pragma unroll
  for (int ty = 0; ty < 3; ++ty)
#pragma unroll
    for (int tx = 0; tx < 3; ++tx) {
      const __half2* ip = (const __half2*)(in + ((size_t)(img * (H + 2) + y + ty) * Wp + x + tx) * 32);
      const float* wpt = &wl[ty * 3 + tx][0];
#pragma unroll
      for (int c2 = 0; c2 < 16; ++c2) {
        float2 v = __half22float2(ip[c2]);
        acc += v.x * wpt[2 * c2];
        acc += v.y * wpt[2 * c2 + 1];
      }
    }
  out[gid] = sub ? (src[gid] - acc) : acc;
}

// ---------------------------------------------------------------------------
static inline int cdiv(int a, int b) { return (a + b - 1) / b; }

extern "C" void kernel_launch(void* const* d_in, const int* in_sizes, int n_in,
                              void* d_out, int out_size, void* d_ws, size_t ws_size,
                              hipStream_t stream) {
  const float* d_inputs = (const float*)d_in[0];
  const float* d_A      = (const float*)d_in[1];
  const float* d_Q      = (const float*)d_in[2];   // Q == A^T, [1089][272] row-major
  const float* d_steps  = (const float*)d_in[3];
  const float* den_w1 = (const float*)d_in[4];
  const float* den_b1 = (const float*)d_in[5];
  const float* den_w2 = (const float*)d_in[6];
  const float* den_b2 = (const float*)d_in[7];
  const float* den_w3 = (const float*)d_in[8];
  const float* den_b3 = (const float*)d_in[9];
  const float* den_w4 = (const float*)d_in[10];
  const float* deb_w1 = (const float*)d_in[11];
  const float* deb_b1 = (const float*)d_in[12];
  const float* deb_w2 = (const float*)d_in[13];
  const float* deb_b2 = (const float*)d_in[14];
  const float* deb_w3 = (const float*)d_in[15];
  const float* deb_b3 = (const float*)d_in[16];
  const float* deb_w4 = (const float*)d_in[17];

  int layers = in_sizes[3];                 // 5
  int M      = in_sizes[1] / NBB;           // 272
  int S      = in_sizes[0] / (IMW * IMW);   // 8
  int N      = 64 * S;                      // 512 block-columns

  // ---- workspace layout (all regions 64B aligned) ----
  float* ws    = (float*)d_ws;
  float* AtA   = ws;                         // 1089*1089 -> padded 1185936
  float* X     = AtA + 1185936;
  float* y2    = X + (size_t)N * NBB;        // [N][M]
  float* r2    = y2 + (size_t)N * M;
  float* z     = r2 + (size_t)N * M;         // [N][1089]
  float* noise = z + (size_t)N * NBB;
  float* img   = noise + (size_t)N * NBB;    // [S][264][264]
  __half* wph  = (__half*)(img + (size_t)S * IMW * IMW);   // layers*4*9216 fp16
  __half* buf1 = wph + (size_t)layers * 4 * 9216 + 4096;   // activation buffers fp16
  size_t bufElems = (size_t)N * 35 * 35 * 32;  // >= S*266*266*32
  __half* buf2 = buf1 + bufElems;

  dim3 blk(256);

  // ---- setup ----
  pack_w_k<<<cdiv(layers * 4 * 9216, 256), blk, 0, stream>>>(den_w2, den_w3, deb_w2, deb_w3, wph, layers);
  // blockify input into z (temp)
  blockify_k<<<cdiv(N * NBB, 256), blk, 0, stream>>>(d_inputs, z, S);
  // AtA = NT(Q, Q)   [1089][1089], K = M
  gemm_nt<<<dim3(cdiv(NBB, 64), cdiv(NBB, 64)), blk, 0, stream>>>(
      d_Q, d_Q, AtA, NBB, NBB, M, M, M, NBB, 0, nullptr, nullptr, nullptr);
  // y2 = NT(z, A)   [N][M], K = 1089
  gemm_nt<<<dim3(cdiv(M, 64), cdiv(N, 64)), blk, 0, stream>>>(
      z, d_A, y2, N, M, NBB, NBB, NBB, M, 0, nullptr, nullptr, nullptr);
  // X = NT(y2, Q)   [N][1089], K = M
  gemm_nt<<<dim3(cdiv(NBB, 64), cdiv(N, 64)), blk, 0, stream>>>(
      y2, d_Q, X, N, NBB, M, M, M, NBB, 0, nullptr, nullptr, nullptr);

  for (int n = 0; n < layers; ++n) {
    const float* stepp = d_steps + n;
    // r2 = y2 - NT(X, A)
    gemm_nt<<<dim3(cdiv(M, 64), cdiv(N, 64)), blk, 0, stream>>>(
        X, d_A, r2, N, M, NBB, NBB, NBB, M, 1, nullptr, y2, nullptr);
    // z = step*NT(r2, Q) + X
    gemm_nt<<<dim3(cdiv(NBB, 64), cdiv(N, 64)), blk, 0, stream>>>(
        r2, d_Q, z, N, NBB, M, M, M, NBB, 2, stepp, X, nullptr);

    // ---- denoise CNN on X (512 images of 33x33) ----
    zero_borders_k<<<cdiv(N * (2 * 35 + 2 * 33), 256), blk, 0, stream>>>(buf1, buf2, N, BLKSZ, BLKSZ);
    conv1_k<<<cdiv(N * NBB, 256), blk, 0, stream>>>(X, buf1, den_w1 + n * 288, den_b1 + n * 32, N, BLKSZ, BLKSZ);
    conv2_mfma_k<<<cdiv(N * BLKSZ * 2, 4), blk, 0, stream>>>(
        buf1, buf2, wph + (size_t)(n * 4 + 0) * 9216, den_b2 + n * 32, N, BLKSZ, BLKSZ);
    conv2_mfma_k<<<cdiv(N * BLKSZ * 2, 4), blk, 0, stream>>>(
        buf2, buf1, wph + (size_t)(n * 4 + 1) * 9216, den_b3 + n * 32, N, BLKSZ, BLKSZ);
    conv4_k<<<cdiv(N * NBB, 256), blk, 0, stream>>>(buf1, noise, den_w4 + n * 288, nullptr, N, BLKSZ, BLKSZ, 0);

    // X = z - step*NT(noise, AtA) + noise
    gemm_nt<<<dim3(cdiv(NBB, 64), cdiv(N, 64)), blk, 0, stream>>>(
        noise, AtA, X, N, NBB, NBB, NBB, NBB, NBB, 3, stepp, z, noise);

    // img = unblockify(X)
    unblockify_k<<<cdiv(S * IMW * IMW, 256), blk, 0, stream>>>(X, img, S);

    // ---- deblock CNN on img (S images of 264x264) ----
    zero_borders_k<<<cdiv(S * (2 * 266 + 2 * 264), 256), blk, 0, stream>>>(buf1, buf2, S, IMW, IMW);
    conv1_k<<<cdiv(S * IMW * IMW, 256), blk, 0, stream>>>(img, buf1, deb_w1 + n * 288, deb_b1 + n * 32, S, IMW, IMW);
    conv2_mfma_k<<<cdiv(S * IMW * 2, 4), blk, 0, stream>>>(
        buf1, buf2, wph + (size_t)(n * 4 + 2) * 9216, deb_b2 + n * 32, S, IMW, IMW);
    conv2_mfma_k<<<cdiv(S * IMW * 2, 4), blk, 0, stream>>>(
        buf2, buf1, wph + (size_t)(n * 4 + 3) * 9216, deb_b3 + n * 32, S, IMW, IMW);
    conv4_k<<<cdiv(S * IMW * IMW, 256), blk, 0, stream>>>(buf1, img, deb_w4 + n * 288, img, S, IMW, IMW, 1);

    // X = blockify(img)
    blockify_k<<<cdiv(N * NBB, 256), blk, 0, stream>>>(img, X, S);
  }

  // output = unblockify(X)
  unblockify_k<<<cdiv(S * IMW * IMW, 256), blk, 0, stream>>>(X, (float*)d_out, S);
}

// Round 6
// 2095.186 us; speedup vs baseline: 5.5869x; 1.9567x over previous
//
#include <hip/hip_runtime.h>
#include <hip/hip_fp16.h>

// Problem constants (from reference): B=33 blocks, 8x8 blocks per image, S=8 images.
#define BLKSZ 33
#define NBB   1089   // 33*33
#define IMW   264    // 8*33

typedef _Float16 f16x8 __attribute__((ext_vector_type(8)));
typedef float f32x4 __attribute__((ext_vector_type(4)));

// ---------------------------------------------------------------------------
// blockify: img [S][264][264] -> X [N=64*S][1089], n = l*64 + h*8 + s, p=i*33+j
__global__ __launch_bounds__(256) void blockify_k(const float* __restrict__ in,
                                                  float* __restrict__ X, int S) {
  int gid = blockIdx.x * 256 + threadIdx.x;
  int total = S * 64 * NBB;
  if (gid >= total) return;
  int n = gid / NBB, p = gid - n * NBB;
  int l = n >> 6, h = (n >> 3) & 7, s = n & 7;
  int i = p / BLKSZ, j = p - i * BLKSZ;
  X[gid] = in[((size_t)s * IMW + h * BLKSZ + i) * IMW + l * BLKSZ + j];
}

// unblockify: X [N][1089] -> img [S][264][264]
__global__ __launch_bounds__(256) void unblockify_k(const float* __restrict__ X,
                                                    float* __restrict__ out, int S) {
  int gid = blockIdx.x * 256 + threadIdx.x;
  int total = S * IMW * IMW;
  if (gid >= total) return;
  int s = gid / (IMW * IMW);
  int rem = gid - s * IMW * IMW;
  int y = rem / IMW, x = rem - y * IMW;
  int h = y / BLKSZ, i = y - h * BLKSZ;
  int l = x / BLKSZ, j = x - l * BLKSZ;
  out[gid] = X[(size_t)(l * 64 + h * 8 + s) * NBB + i * BLKSZ + j];
}

// ---------------------------------------------------------------------------
// Split-K NT GEMM partial: P[sk][i][j] = sum_{k in chunk} A[i,k]*B[j,k]
// grid = (cdiv(N,64), cdiv(M,64), SK). Register-prefetch software pipeline.
__global__ __launch_bounds__(256) void gemm_nt_sk(
    const float* __restrict__ Am, const float* __restrict__ Bm,
    float* __restrict__ P, int M, int N, int K, int lda, int ldb, int SK) {
  __shared__ float As[16][68];  // [k][row]
  __shared__ float Bs[16][68];
  int tid = threadIdx.x;
  int tx = tid & 15, ty = tid >> 4;
  int bi = blockIdx.y * 64, bj = blockIdx.x * 64;
  int sk = blockIdx.z;
  int chunk = (((K + SK - 1) / SK) + 15) & ~15;
  int kbeg = sk * chunk;
  int kend = kbeg + chunk; if (kend > K) kend = K;
  float acc[4][4] = {{0.f, 0.f, 0.f, 0.f}, {0.f, 0.f, 0.f, 0.f},
                     {0.f, 0.f, 0.f, 0.f}, {0.f, 0.f, 0.f, 0.f}};
  float ra[4], rb[4];
  // prefetch first tile into registers  (c = tx is constant; r = ty + t*16)
  {
    int kk = kbeg + tx;
#pragma unroll
    for (int t = 0; t < 4; ++t) {
      int r = ty + t * 16;
      ra[t] = (bi + r < M && kk < kend) ? Am[(size_t)(bi + r) * lda + kk] : 0.f;
      rb[t] = (bj + r < N && kk < kend) ? Bm[(size_t)(bj + r) * ldb + kk] : 0.f;
    }
  }
  for (int k0 = kbeg; k0 < kend; k0 += 16) {
#pragma unroll
    for (int t = 0; t < 4; ++t) {
      int r = ty + t * 16;
      As[tx][r] = ra[t];
      Bs[tx][r] = rb[t];
    }
    __syncthreads();
    if (k0 + 16 < kend) {   // issue next-tile loads; latency hides under compute
      int kk = k0 + 16 + tx;
#pragma unroll
      for (int t = 0; t < 4; ++t) {
        int r = ty + t * 16;
        ra[t] = (bi + r < M && kk < kend) ? Am[(size_t)(bi + r) * lda + kk] : 0.f;
        rb[t] = (bj + r < N && kk < kend) ? Bm[(size_t)(bj + r) * ldb + kk] : 0.f;
      }
    }
#pragma unroll
    for (int kk = 0; kk < 16; ++kk) {
      float4 av = *(const float4*)&As[kk][ty * 4];
      float4 bv = *(const float4*)&Bs[kk][tx * 4];
      acc[0][0] += av.x * bv.x; acc[0][1] += av.x * bv.y; acc[0][2] += av.x * bv.z; acc[0][3] += av.x * bv.w;
      acc[1][0] += av.y * bv.x; acc[1][1] += av.y * bv.y; acc[1][2] += av.y * bv.z; acc[1][3] += av.y * bv.w;
      acc[2][0] += av.z * bv.x; acc[2][1] += av.z * bv.y; acc[2][2] += av.z * bv.z; acc[2][3] += av.z * bv.w;
      acc[3][0] += av.w * bv.x; acc[3][1] += av.w * bv.y; acc[3][2] += av.w * bv.z; acc[3][3] += av.w * bv.w;
    }
    __syncthreads();
  }
  size_t base = (size_t)sk * M * N;
#pragma unroll
  for (int r = 0; r < 4; ++r) {
    int i = bi + ty * 4 + r;
    if (i >= M) continue;
#pragma unroll
    for (int c = 0; c < 4; ++c) {
      int j = bj + tx * 4 + c;
      if (j < N) P[base + (size_t)i * N + j] = acc[r][c];
    }
  }
}

// ---------------------------------------------------------------------------
// Reduce split-K partials + epilogue.
// mode 0: C = sum (and C2 = sum if C2 != null)
// mode 4: C = src1 - step*sum + step*src2
__global__ __launch_bounds__(256) void reduce_sk_k(
    const float* __restrict__ P, float* __restrict__ C, float* __restrict__ C2,
    long long total, long long stride, int SK, int mode,
    const float* __restrict__ step_ptr, const float* __restrict__ src1,
    const float* __restrict__ src2) {
  long long gid = (long long)blockIdx.x * 256 + threadIdx.x;
  if (gid >= total) return;
  float s = 0.f;
  for (int k = 0; k < SK; ++k) s += P[(size_t)k * stride + gid];
  if (mode == 0) {
    C[gid] = s;
    if (C2) C2[gid] = s;
  } else {
    float st = step_ptr[0];
    C[gid] = src1[gid] - st * s + st * src2[gid];
  }
}

// ---------------------------------------------------------------------------
// Pack conv2-type weights fp32 [co][ci][3][3] -> fp16 [slot][tap][co][ci].
// slot = layer*4 + {0:den_w2, 1:den_w3, 2:deb_w2, 3:deb_w3}
__global__ __launch_bounds__(256) void pack_w_k(const float* __restrict__ w0,
                                                const float* __restrict__ w1,
                                                const float* __restrict__ w2,
                                                const float* __restrict__ w3,
                                                __half* __restrict__ wp, int layers) {
  int gid = blockIdx.x * 256 + threadIdx.x;
  int total = layers * 4 * 9216;
  if (gid >= total) return;
  int slot = gid / 9216, r = gid - slot * 9216;
  int n = slot >> 2, which = slot & 3;
  int tap = r / 1024, r2 = r - tap * 1024;
  int co = r2 >> 5, ci = r2 & 31;
  const float* src = (which == 0) ? w0 : (which == 1) ? w1 : (which == 2) ? w2 : w3;
  wp[gid] = __float2half(src[n * 9216 + (co * 32 + ci) * 9 + tap]);
}

// ---------------------------------------------------------------------------
// Zero the 1-px halo border cells of two NHWC(32) fp16 buffers, geometry (nimg,H,W).
__global__ __launch_bounds__(256) void zero_borders_k(__half* __restrict__ a,
                                                      __half* __restrict__ b,
                                                      int nimg, int H, int W) {
  int Wp = W + 2, Hp = H + 2;
  int perim = 2 * Wp + 2 * H;
  int gid = blockIdx.x * 256 + threadIdx.x;
  int total = nimg * perim;
  if (gid >= total) return;
  int img = gid / perim, k = gid - img * perim;
  int row, col;
  if (k < Wp)            { row = 0;      col = k; }
  else if (k < 2 * Wp)   { row = Hp - 1; col = k - Wp; }
  else { int k2 = k - 2 * Wp; row = 1 + (k2 >> 1); col = (k2 & 1) ? (Wp - 1) : 0; }
  size_t off = ((size_t)(img * Hp + row) * Wp + col) * 32;  // halves; 64B aligned
  float4 z = {0.f, 0.f, 0.f, 0.f};
  float4* pa = (float4*)(a + off);
  float4* pb = (float4*)(b + off);
#pragma unroll
  for (int q = 0; q < 4; ++q) { pa[q] = z; pb[q] = z; }
}

// ---------------------------------------------------------------------------
// conv1: planar fp32 [nimg][H][W] -> padded NHWC fp16 [nimg][H+2][W+2][32], relu(conv+bias)
__global__ __launch_bounds__(256) void conv1_k(const float* __restrict__ in,
                                               __half* __restrict__ out,
                                               const float* __restrict__ w,   // [32][1][3][3]
                                               const float* __restrict__ b,
                                               int nimg, int H, int W) {
  __shared__ float wl[9][32];  // [tap][co]
  __shared__ float bl[32];
  int tid = threadIdx.x;
  for (int t = tid; t < 288; t += 256) {
    int co = t / 9, tap = t - co * 9;
    wl[tap][co] = w[t];
  }
  if (tid < 32) bl[tid] = b[tid];
  __syncthreads();
  int gid = blockIdx.x * 256 + tid;
  if (gid >= nimg * H * W) return;
  int img = gid / (H * W);
  int rem = gid - img * H * W;
  int y = rem / W, x = rem - y * W;
  float acc[32];
#pragma unroll
  for (int c = 0; c < 32; ++c) acc[c] = bl[c];
  const float* ip = in + (size_t)img * H * W;
#pragma unroll
  for (int ty = 0; ty < 3; ++ty)
#pragma unroll
    for (int tx = 0; tx < 3; ++tx) {
      int yy = y + ty - 1, xx = x + tx - 1;
      if (yy >= 0 && yy < H && xx >= 0 && xx < W) {
        float v = ip[(size_t)yy * W + xx];
        const float* wp = &wl[ty * 3 + tx][0];
#pragma unroll
        for (int q = 0; q < 8; ++q) {
          float4 wv = *(const float4*)(wp + q * 4);
          acc[q * 4 + 0] += v * wv.x; acc[q * 4 + 1] += v * wv.y;
          acc[q * 4 + 2] += v * wv.z; acc[q * 4 + 3] += v * wv.w;
        }
      }
    }
  size_t ob = ((size_t)(img * (H + 2) + y + 1) * (W + 2) + x + 1) * 32;
  __half2* op = (__half2*)(out + ob);
#pragma unroll
  for (int c2 = 0; c2 < 16; ++c2)
    op[c2] = __floats2half2_rn(fmaxf(acc[2 * c2], 0.f), fmaxf(acc[2 * c2 + 1], 0.f));
}

// ---------------------------------------------------------------------------
// conv2 via MFMA fp16 implicit GEMM: padded NHWC fp16 -> padded NHWC fp16,
// 32->32, relu(conv+bias). One wave = 16 px x 16 co tile; loops x-tiles of a row.
__global__ __launch_bounds__(256) void conv2_mfma_k(const __half* __restrict__ in,
                                                    __half* __restrict__ out,
                                                    const __half* __restrict__ wp,  // [9][32][32]
                                                    const float* __restrict__ bias,
                                                    int nimg, int H, int W) {
  int wid = blockIdx.x * 4 + (threadIdx.x >> 6);
  int total = nimg * H * 2;
  if (wid >= total) return;
  int lane = threadIdx.x & 63;
  int m16 = lane & 15, kg = lane >> 4;
  int cohalf = wid & 1;
  int t = wid >> 1;
  int y = t % H;
  int img = t / H;
  int Wp = W + 2, Hp = H + 2;
  f16x8 bfr[9];
#pragma unroll
  for (int tap = 0; tap < 9; ++tap)
    bfr[tap] = *(const f16x8*)(wp + ((tap * 32 + cohalf * 16 + m16) * 32 + kg * 8));
  float bv = bias[cohalf * 16 + m16];
  int ntx = (W + 15) >> 4;
  size_t ibase = (size_t)img * Hp * Wp;
  for (int xt = 0; xt < ntx; ++xt) {
    int x0 = xt << 4;
    f32x4 acc0 = {0.f, 0.f, 0.f, 0.f};
    f32x4 acc1 = {0.f, 0.f, 0.f, 0.f};
#pragma unroll
    for (int ty = 0; ty < 3; ++ty) {
      size_t rbase = ibase + (size_t)(y + ty) * Wp;
#pragma unroll
      for (int tx = 0; tx < 3; ++tx) {
        int col = x0 + m16 + tx;
        if (col > W + 1) col = W + 1;
        f16x8 afr = *(const f16x8*)(in + (rbase + col) * 32 + kg * 8);
        if (((ty * 3 + tx) & 1) == 0)
          acc0 = __builtin_amdgcn_mfma_f32_16x16x32_f16(afr, bfr[ty * 3 + tx], acc0, 0, 0, 0);
        else
          acc1 = __builtin_amdgcn_mfma_f32_16x16x32_f16(afr, bfr[ty * 3 + tx], acc1, 0, 0, 0);
      }
    }
#pragma unroll
    for (int r = 0; r < 4; ++r) {
      int p = kg * 4 + r;
      int xo = x0 + p;
      if (xo < W) {
        float v = fmaxf(acc0[r] + acc1[r] + bv, 0.f);
        out[(ibase + (size_t)(y + 1) * Wp + (xo + 1)) * 32 + cohalf * 16 + m16] = __float2half(v);
      }
    }
  }
}

// ---------------------------------------------------------------------------
// conv4: padded NHWC fp16 -> planar fp32, 32->1, no bias, no relu.
// out = src + sign*conv   (denoise: src=X, sign=+1 -> T = X + noise;
//                          deblock: src=img, sign=-1 -> img - conv)
__global__ __launch_bounds__(256) void conv4_k(const __half* __restrict__ in,
                                               float* __restrict__ out,
                                               const float* __restrict__ w,   // [1][32][3][3]
                                               const float* __restrict__ src,
                                               int nimg, int H, int W, float sign) {
  __shared__ float wl[9][32];  // [tap][ci]
  int tid = threadIdx.x;
  for (int t = tid; t < 288; t += 256) {
    int ci = t / 9, tap = t - ci * 9;
    wl[tap][ci] = w[t];
  }
  __syncthreads();
  int gid = blockIdx.x * 256 + tid;
  if (gid >= nimg * H * W) return;
  int img = gid / (H * W);
  int rem = gid - img * H * W;
  int y = rem / W, x = rem - y * W;
  int Wp = W + 2;
  float acc = 0.f;
#pragma unroll
  for (int ty = 0; ty < 3; ++ty)
#pragma unroll
    for (int tx = 0; tx < 3; ++tx) {
      const __half2* ip = (const __half2*)(in + ((size_t)(img * (H + 2) + y + ty) * Wp + x + tx) * 32);
      const float* wpt = &wl[ty * 3 + tx][0];
#pragma unroll
      for (int c2 = 0; c2 < 16; ++c2) {
        float2 v = __half22float2(ip[c2]);
        acc += v.x * wpt[2 * c2];
        acc += v.y * wpt[2 * c2 + 1];
      }
    }
  out[gid] = src[gid] + sign * acc;
}

// ---------------------------------------------------------------------------
static inline int cdiv(int a, int b) { return (a + b - 1) / b; }

extern "C" void kernel_launch(void* const* d_in, const int* in_sizes, int n_in,
                              void* d_out, int out_size, void* d_ws, size_t ws_size,
                              hipStream_t stream) {
  const float* d_inputs = (const float*)d_in[0];
  const float* d_A      = (const float*)d_in[1];
  const float* d_Q      = (const float*)d_in[2];   // Q == A^T, [1089][272] row-major
  const float* d_steps  = (const float*)d_in[3];
  const float* den_w1 = (const float*)d_in[4];
  const float* den_b1 = (const float*)d_in[5];
  const float* den_b2 = (const float*)d_in[7];
  const float* den_b3 = (const float*)d_in[9];
  const float* den_w4 = (const float*)d_in[10];
  const float* deb_w1 = (const float*)d_in[11];
  const float* deb_b1 = (const float*)d_in[12];
  const float* deb_b2 = (const float*)d_in[14];
  const float* deb_b3 = (const float*)d_in[16];
  const float* deb_w4 = (const float*)d_in[17];

  int layers = in_sizes[3];                 // 5
  int M      = in_sizes[1] / NBB;           // 272
  int S      = in_sizes[0] / (IMW * IMW);   // 8
  int N      = 64 * S;                      // 512 block-columns

  // ---- workspace layout (region sizes in floats; all 64B-aligned) ----
  float* ws    = (float*)d_ws;
  float* AtA   = ws;                           // 1089*1089 (pad to 1185936)
  float* X     = AtA + 1185936;                // [N][1089]
  float* T     = X + (size_t)N * NBB;          // [N][1089]  (X + noise; also Xb temp)
  float* X0    = T + (size_t)N * NBB;          // [N][1089]
  float* y2    = X0 + (size_t)N * NBB;         // [N][M]
  float* img   = y2 + (size_t)N * M;           // [S][264][264]
  float* Pbuf  = img + (size_t)S * IMW * IMW;  // split-K partials, max 8*N*NBB
  __half* wph  = (__half*)(Pbuf + (size_t)8 * N * NBB);
  __half* buf1 = wph + (size_t)layers * 4 * 9216 + 2048;
  size_t bufElems = (size_t)N * 35 * 35 * 32;  // >= S*266*266*32
  __half* buf2 = buf1 + bufElems;

  dim3 blk(256);

  // ---- setup ----
  pack_w_k<<<cdiv(layers * 4 * 9216, 256), blk, 0, stream>>>(
      (const float*)d_in[6], (const float*)d_in[8], (const float*)d_in[13],
      (const float*)d_in[15], wph, layers);
  blockify_k<<<cdiv(N * NBB, 256), blk, 0, stream>>>(d_inputs, T, S);  // T = Xb

  // AtA = NT(Q,Q)  [1089x1089], K=M, SK=2
  gemm_nt_sk<<<dim3(cdiv(NBB, 64), cdiv(NBB, 64), 2), blk, 0, stream>>>(
      d_Q, d_Q, Pbuf, NBB, NBB, M, M, M, 2);
  reduce_sk_k<<<cdiv(NBB * NBB, 256), blk, 0, stream>>>(
      Pbuf, AtA, nullptr, (long long)NBB * NBB, (long long)NBB * NBB, 2, 0,
      nullptr, nullptr, nullptr);
  // y2 = NT(Xb, A)  [N x M], K=1089, SK=8
  gemm_nt_sk<<<dim3(cdiv(M, 64), cdiv(N, 64), 8), blk, 0, stream>>>(
      T, d_A, Pbuf, N, M, NBB, NBB, NBB, 8);
  reduce_sk_k<<<cdiv(N * M, 256), blk, 0, stream>>>(
      Pbuf, y2, nullptr, (long long)N * M, (long long)N * M, 8, 0,
      nullptr, nullptr, nullptr);
  // X0 = NT(y2, Q)  [N x 1089], K=M, SK=4; dual-write X = X0
  gemm_nt_sk<<<dim3(cdiv(NBB, 64), cdiv(N, 64), 4), blk, 0, stream>>>(
      y2, d_Q, Pbuf, N, NBB, M, M, M, 4);
  reduce_sk_k<<<cdiv(N * NBB, 256), blk, 0, stream>>>(
      Pbuf, X0, X, (long long)N * NBB, (long long)N * NBB, 4, 0,
      nullptr, nullptr, nullptr);

  for (int n = 0; n < layers; ++n) {
    const float* stepp = d_steps + n;

    // ---- denoise CNN on X (512 images of 33x33); conv4 emits T = X + noise ----
    zero_borders_k<<<cdiv(N * (2 * 35 + 2 * 33), 256), blk, 0, stream>>>(buf1, buf2, N, BLKSZ, BLKSZ);
    conv1_k<<<cdiv(N * NBB, 256), blk, 0, stream>>>(X, buf1, den_w1 + n * 288, den_b1 + n * 32, N, BLKSZ, BLKSZ);
    conv2_mfma_k<<<cdiv(N * BLKSZ * 2, 4), blk, 0, stream>>>(
        buf1, buf2, wph + (size_t)(n * 4 + 0) * 9216, den_b2 + n * 32, N, BLKSZ, BLKSZ);
    conv2_mfma_k<<<cdiv(N * BLKSZ * 2, 4), blk, 0, stream>>>(
        buf2, buf1, wph + (size_t)(n * 4 + 1) * 9216, den_b3 + n * 32, N, BLKSZ, BLKSZ);
    conv4_k<<<cdiv(N * NBB, 256), blk, 0, stream>>>(buf1, T, den_w4 + n * 288, X, N, BLKSZ, BLKSZ, 1.f);

    // ---- X = T - step*(T@AtA) + step*X0   (one NT-GEMM, K=1089, SK=8) ----
    gemm_nt_sk<<<dim3(cdiv(NBB, 64), cdiv(N, 64), 8), blk, 0, stream>>>(
        T, AtA, Pbuf, N, NBB, NBB, NBB, NBB, 8);
    reduce_sk_k<<<cdiv(N * NBB, 256), blk, 0, stream>>>(
        Pbuf, X, nullptr, (long long)N * NBB, (long long)N * NBB, 8, 4,
        stepp, T, X0);

    // img = unblockify(X)
    unblockify_k<<<cdiv(S * IMW * IMW, 256), blk, 0, stream>>>(X, img, S);

    // ---- deblock CNN on img (S images of 264x264) ----
    zero_borders_k<<<cdiv(S * (2 * 266 + 2 * 264), 256), blk, 0, stream>>>(buf1, buf2, S, IMW, IMW);
    conv1_k<<<cdiv(S * IMW * IMW, 256), blk, 0, stream>>>(img, buf1, deb_w1 + n * 288, deb_b1 + n * 32, S, IMW, IMW);
    conv2_mfma_k<<<cdiv(S * IMW * 2, 4), blk, 0, stream>>>(
        buf1, buf2, wph + (size_t)(n * 4 + 2) * 9216, deb_b2 + n * 32, S, IMW, IMW);
    conv2_mfma_k<<<cdiv(S * IMW * 2, 4), blk, 0, stream>>>(
        buf2, buf1, wph + (size_t)(n * 4 + 3) * 9216, deb_b3 + n * 32, S, IMW, IMW);
    conv4_k<<<cdiv(S * IMW * IMW, 256), blk, 0, stream>>>(buf1, img, deb_w4 + n * 288, img, S, IMW, IMW, -1.f);

    // X = blockify(img)
    blockify_k<<<cdiv(N * NBB, 256), blk, 0, stream>>>(img, X, S);
  }

  // output = unblockify(X)
  unblockify_k<<<cdiv(S * IMW * IMW, 256), blk, 0, stream>>>(X, (float*)d_out, S);
}

// Round 7
// 1517.563 us; speedup vs baseline: 7.7135x; 1.3806x over previous
//
#include <hip/hip_runtime.h>
#include <hip/hip_fp16.h>

// Problem constants (from reference): B=33 blocks, 8x8 blocks per image, S=8 images.
#define BLKSZ 33
#define NBB   1089   // 33*33
#define IMW   264    // 8*33

typedef _Float16 f16x8 __attribute__((ext_vector_type(8)));
typedef float f32x4 __attribute__((ext_vector_type(4)));

// ---------------------------------------------------------------------------
// blockify: img [S][264][264] -> X [N=64*S][1089], n = l*64 + h*8 + s, p=i*33+j
__global__ __launch_bounds__(256) void blockify_k(const float* __restrict__ in,
                                                  float* __restrict__ X, int S) {
  int gid = blockIdx.x * 256 + threadIdx.x;
  int total = S * 64 * NBB;
  if (gid >= total) return;
  int n = gid / NBB, p = gid - n * NBB;
  int l = n >> 6, h = (n >> 3) & 7, s = n & 7;
  int i = p / BLKSZ, j = p - i * BLKSZ;
  X[gid] = in[((size_t)s * IMW + h * BLKSZ + i) * IMW + l * BLKSZ + j];
}

// unblockify: X [N][1089] -> img [S][264][264]
__global__ __launch_bounds__(256) void unblockify_k(const float* __restrict__ X,
                                                    float* __restrict__ out, int S) {
  int gid = blockIdx.x * 256 + threadIdx.x;
  int total = S * IMW * IMW;
  if (gid >= total) return;
  int s = gid / (IMW * IMW);
  int rem = gid - s * IMW * IMW;
  int y = rem / IMW, x = rem - y * IMW;
  int h = y / BLKSZ, i = y - h * BLKSZ;
  int l = x / BLKSZ, j = x - l * BLKSZ;
  out[gid] = X[(size_t)(l * 64 + h * 8 + s) * NBB + i * BLKSZ + j];
}

// ---------------------------------------------------------------------------
// Split-K NT GEMM partial: P[sk][i][j] = sum_{k in chunk} A[i,k]*B[j,k]
__global__ __launch_bounds__(256) void gemm_nt_sk(
    const float* __restrict__ Am, const float* __restrict__ Bm,
    float* __restrict__ P, int M, int N, int K, int lda, int ldb, int SK) {
  __shared__ float As[16][68];  // [k][row]
  __shared__ float Bs[16][68];
  int tid = threadIdx.x;
  int tx = tid & 15, ty = tid >> 4;
  int bi = blockIdx.y * 64, bj = blockIdx.x * 64;
  int sk = blockIdx.z;
  int chunk = (((K + SK - 1) / SK) + 15) & ~15;
  int kbeg = sk * chunk;
  int kend = kbeg + chunk; if (kend > K) kend = K;
  float acc[4][4] = {{0.f, 0.f, 0.f, 0.f}, {0.f, 0.f, 0.f, 0.f},
                     {0.f, 0.f, 0.f, 0.f}, {0.f, 0.f, 0.f, 0.f}};
  float ra[4], rb[4];
  {
    int kk = kbeg + tx;
#pragma unroll
    for (int t = 0; t < 4; ++t) {
      int r = ty + t * 16;
      ra[t] = (bi + r < M && kk < kend) ? Am[(size_t)(bi + r) * lda + kk] : 0.f;
      rb[t] = (bj + r < N && kk < kend) ? Bm[(size_t)(bj + r) * ldb + kk] : 0.f;
    }
  }
  for (int k0 = kbeg; k0 < kend; k0 += 16) {
#pragma unroll
    for (int t = 0; t < 4; ++t) {
      int r = ty + t * 16;
      As[tx][r] = ra[t];
      Bs[tx][r] = rb[t];
    }
    __syncthreads();
    if (k0 + 16 < kend) {
      int kk = k0 + 16 + tx;
#pragma unroll
      for (int t = 0; t < 4; ++t) {
        int r = ty + t * 16;
        ra[t] = (bi + r < M && kk < kend) ? Am[(size_t)(bi + r) * lda + kk] : 0.f;
        rb[t] = (bj + r < N && kk < kend) ? Bm[(size_t)(bj + r) * ldb + kk] : 0.f;
      }
    }
#pragma unroll
    for (int kk = 0; kk < 16; ++kk) {
      float4 av = *(const float4*)&As[kk][ty * 4];
      float4 bv = *(const float4*)&Bs[kk][tx * 4];
      acc[0][0] += av.x * bv.x; acc[0][1] += av.x * bv.y; acc[0][2] += av.x * bv.z; acc[0][3] += av.x * bv.w;
      acc[1][0] += av.y * bv.x; acc[1][1] += av.y * bv.y; acc[1][2] += av.y * bv.z; acc[1][3] += av.y * bv.w;
      acc[2][0] += av.z * bv.x; acc[2][1] += av.z * bv.y; acc[2][2] += av.z * bv.z; acc[2][3] += av.z * bv.w;
      acc[3][0] += av.w * bv.x; acc[3][1] += av.w * bv.y; acc[3][2] += av.w * bv.z; acc[3][3] += av.w * bv.w;
    }
    __syncthreads();
  }
  size_t base = (size_t)sk * M * N;
#pragma unroll
  for (int r = 0; r < 4; ++r) {
    int i = bi + ty * 4 + r;
    if (i >= M) continue;
#pragma unroll
    for (int c = 0; c < 4; ++c) {
      int j = bj + tx * 4 + c;
      if (j < N) P[base + (size_t)i * N + j] = acc[r][c];
    }
  }
}

// ---------------------------------------------------------------------------
// Reduce split-K partials + epilogue.
// mode 0: C = sum (and C2 = sum if C2 != null)
// mode 4: C = src1 - step*sum + step*src2
__global__ __launch_bounds__(256) void reduce_sk_k(
    const float* __restrict__ P, float* __restrict__ C, float* __restrict__ C2,
    long long total, long long stride, int SK, int mode,
    const float* __restrict__ step_ptr, const float* __restrict__ src1,
    const float* __restrict__ src2) {
  long long gid = (long long)blockIdx.x * 256 + threadIdx.x;
  if (gid >= total) return;
  float s = 0.f;
  for (int k = 0; k < SK; ++k) s += P[(size_t)k * stride + gid];
  if (mode == 0) {
    C[gid] = s;
    if (C2) C2[gid] = s;
  } else {
    float st = step_ptr[0];
    C[gid] = src1[gid] - st * s + st * src2[gid];
  }
}

// ---------------------------------------------------------------------------
// Pack conv2-type weights fp32 [co][ci][3][3] -> fp16 [slot][tap][co][ci].
// slot = layer*4 + {0:den_w2, 1:den_w3, 2:deb_w2, 3:deb_w3}
__global__ __launch_bounds__(256) void pack_w_k(const float* __restrict__ w0,
                                                const float* __restrict__ w1,
                                                const float* __restrict__ w2,
                                                const float* __restrict__ w3,
                                                __half* __restrict__ wp, int layers) {
  int gid = blockIdx.x * 256 + threadIdx.x;
  int total = layers * 4 * 9216;
  if (gid >= total) return;
  int slot = gid / 9216, r = gid - slot * 9216;
  int n = slot >> 2, which = slot & 3;
  int tap = r / 1024, r2 = r - tap * 1024;
  int co = r2 >> 5, ci = r2 & 31;
  const float* src = (which == 0) ? w0 : (which == 1) ? w1 : (which == 2) ? w2 : w3;
  wp[gid] = __float2half(src[n * 9216 + (co * 32 + ci) * 9 + tap]);
}

// ---------------------------------------------------------------------------
// Zero the 1-px halo border cells of two NHWC(32) fp16 buffers, geometry (nimg,H,W).
__global__ __launch_bounds__(256) void zero_borders_k(__half* __restrict__ a,
                                                      __half* __restrict__ b,
                                                      int nimg, int H, int W) {
  int Wp = W + 2, Hp = H + 2;
  int perim = 2 * Wp + 2 * H;
  int gid = blockIdx.x * 256 + threadIdx.x;
  int total = nimg * perim;
  if (gid >= total) return;
  int img = gid / perim, k = gid - img * perim;
  int row, col;
  if (k < Wp)            { row = 0;      col = k; }
  else if (k < 2 * Wp)   { row = Hp - 1; col = k - Wp; }
  else { int k2 = k - 2 * Wp; row = 1 + (k2 >> 1); col = (k2 & 1) ? (Wp - 1) : 0; }
  size_t off = ((size_t)(img * Hp + row) * Wp + col) * 32;  // halves; 64B aligned
  float4 z = {0.f, 0.f, 0.f, 0.f};
  float4* pa = (float4*)(a + off);
  float4* pb = (float4*)(b + off);
#pragma unroll
  for (int q = 0; q < 4; ++q) { pa[q] = z; pb[q] = z; }
}

// ---------------------------------------------------------------------------
// conv1: planar fp32 [nimg][H][W] -> padded NHWC fp16 [nimg][H+2][W+2][32], relu(conv+bias)
__global__ __launch_bounds__(256) void conv1_k(const float* __restrict__ in,
                                               __half* __restrict__ out,
                                               const float* __restrict__ w,   // [32][1][3][3]
                                               const float* __restrict__ b,
                                               int nimg, int H, int W) {
  __shared__ float wl[9][32];  // [tap][co]
  __shared__ float bl[32];
  int tid = threadIdx.x;
  for (int t = tid; t < 288; t += 256) {
    int co = t / 9, tap = t - co * 9;
    wl[tap][co] = w[t];
  }
  if (tid < 32) bl[tid] = b[tid];
  __syncthreads();
  int gid = blockIdx.x * 256 + tid;
  if (gid >= nimg * H * W) return;
  int img = gid / (H * W);
  int rem = gid - img * H * W;
  int y = rem / W, x = rem - y * W;
  float acc[32];
#pragma unroll
  for (int c = 0; c < 32; ++c) acc[c] = bl[c];
  const float* ip = in + (size_t)img * H * W;
#pragma unroll
  for (int ty = 0; ty < 3; ++ty)
#pragma unroll
    for (int tx = 0; tx < 3; ++tx) {
      int yy = y + ty - 1, xx = x + tx - 1;
      if (yy >= 0 && yy < H && xx >= 0 && xx < W) {
        float v = ip[(size_t)yy * W + xx];
        const float* wp = &wl[ty * 3 + tx][0];
#pragma unroll
        for (int q = 0; q < 8; ++q) {
          float4 wv = *(const float4*)(wp + q * 4);
          acc[q * 4 + 0] += v * wv.x; acc[q * 4 + 1] += v * wv.y;
          acc[q * 4 + 2] += v * wv.z; acc[q * 4 + 3] += v * wv.w;
        }
      }
    }
  size_t ob = ((size_t)(img * (H + 2) + y + 1) * (W + 2) + x + 1) * 32;
  __half2* op = (__half2*)(out + ob);
#pragma unroll
  for (int c2 = 0; c2 < 16; ++c2)
    op[c2] = __floats2half2_rn(fmaxf(acc[2 * c2], 0.f), fmaxf(acc[2 * c2 + 1], 0.f));
}

// ---------------------------------------------------------------------------
// conv2 via MFMA fp16 implicit GEMM, y-marching version.
// Wave owns (img, cohalf, x-tile of 16 px, y-chunk of CH rows) and marches down
// rows keeping a 5-row ring of A-fragments in registers (distance-3 prefetch).
// Per row-step: 3 new 16B loads, 9 MFMAs, 1 output row stored.
__global__ __launch_bounds__(256) void conv2_mfma_k(const __half* __restrict__ in,
                                                    __half* __restrict__ out,
                                                    const __half* __restrict__ wp,  // [9][32][32]
                                                    const float* __restrict__ bias,
                                                    int nimg, int H, int W, int CH) {
  int ntx = (W + 15) >> 4;
  int nch = (H + CH - 1) / CH;
  int wid = blockIdx.x * 4 + (threadIdx.x >> 6);
  int total = nimg * 2 * ntx * nch;
  if (wid >= total) return;
  int lane = threadIdx.x & 63;
  int m16 = lane & 15, kg = lane >> 4;
  int yc = wid % nch; int t = wid / nch;
  int xt = t % ntx; t /= ntx;
  int cohalf = t & 1; int img = t >> 1;
  int Wp = W + 2, Hp = H + 2, Hpm1 = Hp - 1;
  // B fragments (held whole chunk)
  const __half* wq = wp + (cohalf * 16 + m16) * 32 + kg * 8;
  f16x8 bfr0 = *(const f16x8*)(wq + 0 * 1024);
  f16x8 bfr1 = *(const f16x8*)(wq + 1 * 1024);
  f16x8 bfr2 = *(const f16x8*)(wq + 2 * 1024);
  f16x8 bfr3 = *(const f16x8*)(wq + 3 * 1024);
  f16x8 bfr4 = *(const f16x8*)(wq + 4 * 1024);
  f16x8 bfr5 = *(const f16x8*)(wq + 5 * 1024);
  f16x8 bfr6 = *(const f16x8*)(wq + 6 * 1024);
  f16x8 bfr7 = *(const f16x8*)(wq + 7 * 1024);
  f16x8 bfr8 = *(const f16x8*)(wq + 8 * 1024);
  float bv = bias[cohalf * 16 + m16];
  int x0 = xt << 4;
  int y1 = yc * CH + 1;            // first output padded row
  int y2 = y1 + CH - 1; if (y2 > H) y2 = H;
  int c0 = x0 + m16;     if (c0 > W + 1) c0 = W + 1; c0 *= 32;
  int c1 = x0 + m16 + 1; if (c1 > W + 1) c1 = W + 1; c1 *= 32;
  int c2 = x0 + m16 + 2; if (c2 > W + 1) c2 = W + 1; c2 *= 32;
  size_t ibase = (size_t)img * Hp;
  int cohalf16 = cohalf * 16;

#define LOADROW(row, d0, d1, d2) { int rr = (row); if (rr > Hpm1) rr = Hpm1;    \
    const __half* rp = in + (ibase + rr) * (size_t)Wp * 32 + kg * 8;            \
    d0 = *(const f16x8*)(rp + c0); d1 = *(const f16x8*)(rp + c1);               \
    d2 = *(const f16x8*)(rp + c2); }

#define CITER(yo, A0_,A1_,A2_, B0_,B1_,B2_, C0_,C1_,C2_, P0_,P1_,P2_) {         \
    LOADROW((yo) + 3, P0_, P1_, P2_);                                           \
    f32x4 a0 = {0.f, 0.f, 0.f, 0.f}, a1 = {0.f, 0.f, 0.f, 0.f};                 \
    a0 = __builtin_amdgcn_mfma_f32_16x16x32_f16(A0_, bfr0, a0, 0, 0, 0);        \
    a1 = __builtin_amdgcn_mfma_f32_16x16x32_f16(A1_, bfr1, a1, 0, 0, 0);        \
    a0 = __builtin_amdgcn_mfma_f32_16x16x32_f16(A2_, bfr2, a0, 0, 0, 0);        \
    a1 = __builtin_amdgcn_mfma_f32_16x16x32_f16(B0_, bfr3, a1, 0, 0, 0);        \
    a0 = __builtin_amdgcn_mfma_f32_16x16x32_f16(B1_, bfr4, a0, 0, 0, 0);        \
    a1 = __builtin_amdgcn_mfma_f32_16x16x32_f16(B2_, bfr5, a1, 0, 0, 0);        \
    a0 = __builtin_amdgcn_mfma_f32_16x16x32_f16(C0_, bfr6, a0, 0, 0, 0);        \
    a1 = __builtin_amdgcn_mfma_f32_16x16x32_f16(C1_, bfr7, a1, 0, 0, 0);        \
    a0 = __builtin_amdgcn_mfma_f32_16x16x32_f16(C2_, bfr8, a0, 0, 0, 0);        \
    __half* op = out + (ibase + (yo)) * (size_t)Wp * 32 + cohalf16 + m16;       \
    _Pragma("unroll")                                                           \
    for (int r = 0; r < 4; ++r) { int xo = x0 + kg * 4 + r;                     \
      if (xo < W) op[(xo + 1) * 32] = __float2half(fmaxf(a0[r] + a1[r] + bv, 0.f)); } }

  f16x8 A0,A1,A2,B0,B1,B2,C0,C1,C2,D0,D1,D2,E0,E1,E2;
  LOADROW(y1 - 1, A0, A1, A2);
  LOADROW(y1,     B0, B1, B2);
  LOADROW(y1 + 1, C0, C1, C2);
  LOADROW(y1 + 2, D0, D1, D2);
  int yo = y1;
  for (; yo + 4 <= y2; yo += 5) {
    CITER(yo,     A0,A1,A2, B0,B1,B2, C0,C1,C2, E0,E1,E2);
    CITER(yo + 1, B0,B1,B2, C0,C1,C2, D0,D1,D2, A0,A1,A2);
    CITER(yo + 2, C0,C1,C2, D0,D1,D2, E0,E1,E2, B0,B1,B2);
    CITER(yo + 3, D0,D1,D2, E0,E1,E2, A0,A1,A2, C0,C1,C2);
    CITER(yo + 4, E0,E1,E2, A0,A1,A2, B0,B1,B2, D0,D1,D2);
  }
  if (yo <= y2) { CITER(yo, A0,A1,A2, B0,B1,B2, C0,C1,C2, E0,E1,E2); ++yo; }
  if (yo <= y2) { CITER(yo, B0,B1,B2, C0,C1,C2, D0,D1,D2, A0,A1,A2); ++yo; }
  if (yo <= y2) { CITER(yo, C0,C1,C2, D0,D1,D2, E0,E1,E2, B0,B1,B2); ++yo; }
  if (yo <= y2) { CITER(yo, D0,D1,D2, E0,E1,E2, A0,A1,A2, C0,C1,C2); ++yo; }
#undef CITER
#undef LOADROW
}

// ---------------------------------------------------------------------------
// conv4: padded NHWC fp16 -> planar fp32, 32->1, no bias, no relu.
// out = src + sign*conv
__global__ __launch_bounds__(256) void conv4_k(const __half* __restrict__ in,
                                               float* __restrict__ out,
                                               const float* __restrict__ w,   // [1][32][3][3]
                                               const float* __restrict__ src,
                                               int nimg, int H, int W, float sign) {
  __shared__ float wl[9][32];  // [tap][ci]
  int tid = threadIdx.x;
  for (int t = tid; t < 288; t += 256) {
    int ci = t / 9, tap = t - ci * 9;
    wl[tap][ci] = w[t];
  }
  __syncthreads();
  int gid = blockIdx.x * 256 + tid;
  if (gid >= nimg * H * W) return;
  int img = gid / (H * W);
  int rem = gid - img * H * W;
  int y = rem / W, x = rem - y * W;
  int Wp = W + 2;
  float acc = 0.f;
#pragma unroll
  for (int ty = 0; ty < 3; ++ty)
#pragma unroll
    for (int tx = 0; tx < 3; ++tx) {
      const __half2* ip = (const __half2*)(in + ((size_t)(img * (H + 2) + y + ty) * Wp + x + tx) * 32);
      const float* wpt = &wl[ty * 3 + tx][0];
#pragma unroll
      for (int c2 = 0; c2 < 16; ++c2) {
        float2 v = __half22float2(ip[c2]);
        acc += v.x * wpt[2 * c2];
        acc += v.y * wpt[2 * c2 + 1];
      }
    }
  out[gid] = src[gid] + sign * acc;
}

// ---------------------------------------------------------------------------
static inline int cdiv(int a, int b) { return (a + b - 1) / b; }

extern "C" void kernel_launch(void* const* d_in, const int* in_sizes, int n_in,
                              void* d_out, int out_size, void* d_ws, size_t ws_size,
                              hipStream_t stream) {
  const float* d_inputs = (const float*)d_in[0];
  const float* d_A      = (const float*)d_in[1];
  const float* d_Q      = (const float*)d_in[2];   // Q == A^T, [1089][272] row-major
  const float* d_steps  = (const float*)d_in[3];
  const float* den_w1 = (const float*)d_in[4];
  const float* den_b1 = (const float*)d_in[5];
  const float* den_b2 = (const float*)d_in[7];
  const float* den_b3 = (const float*)d_in[9];
  const float* den_w4 = (const float*)d_in[10];
  const float* deb_w1 = (const float*)d_in[11];
  const float* deb_b1 = (const float*)d_in[12];
  const float* deb_b2 = (const float*)d_in[14];
  const float* deb_b3 = (const float*)d_in[16];
  const float* deb_w4 = (const float*)d_in[17];

  int layers = in_sizes[3];                 // 5
  int M      = in_sizes[1] / NBB;           // 272
  int S      = in_sizes[0] / (IMW * IMW);   // 8
  int N      = 64 * S;                      // 512 block-columns

  // ---- workspace layout (region sizes in floats; all 64B-aligned) ----
  float* ws    = (float*)d_ws;
  float* AtA   = ws;                           // 1089*1089 (pad to 1185936)
  float* X     = AtA + 1185936;                // [N][1089]
  float* T     = X + (size_t)N * NBB;          // [N][1089]  (X + noise; also Xb temp)
  float* X0    = T + (size_t)N * NBB;          // [N][1089]
  float* y2    = X0 + (size_t)N * NBB;         // [N][M]
  float* img   = y2 + (size_t)N * M;           // [S][264][264]
  float* Pbuf  = img + (size_t)S * IMW * IMW;  // split-K partials, max 8*N*NBB
  __half* wph  = (__half*)(Pbuf + (size_t)8 * N * NBB);
  __half* buf1 = wph + (size_t)layers * 4 * 9216 + 2048;
  size_t bufElems = (size_t)N * 35 * 35 * 32;  // >= S*266*266*32
  __half* buf2 = buf1 + bufElems;

  dim3 blk(256);

  // ---- setup ----
  pack_w_k<<<cdiv(layers * 4 * 9216, 256), blk, 0, stream>>>(
      (const float*)d_in[6], (const float*)d_in[8], (const float*)d_in[13],
      (const float*)d_in[15], wph, layers);
  blockify_k<<<cdiv(N * NBB, 256), blk, 0, stream>>>(d_inputs, T, S);  // T = Xb

  // AtA = NT(Q,Q)  [1089x1089], K=M, SK=2
  gemm_nt_sk<<<dim3(cdiv(NBB, 64), cdiv(NBB, 64), 2), blk, 0, stream>>>(
      d_Q, d_Q, Pbuf, NBB, NBB, M, M, M, 2);
  reduce_sk_k<<<cdiv(NBB * NBB, 256), blk, 0, stream>>>(
      Pbuf, AtA, nullptr, (long long)NBB * NBB, (long long)NBB * NBB, 2, 0,
      nullptr, nullptr, nullptr);
  // y2 = NT(Xb, A)  [N x M], K=1089, SK=8
  gemm_nt_sk<<<dim3(cdiv(M, 64), cdiv(N, 64), 8), blk, 0, stream>>>(
      T, d_A, Pbuf, N, M, NBB, NBB, NBB, 8);
  reduce_sk_k<<<cdiv(N * M, 256), blk, 0, stream>>>(
      Pbuf, y2, nullptr, (long long)N * M, (long long)N * M, 8, 0,
      nullptr, nullptr, nullptr);
  // X0 = NT(y2, Q)  [N x 1089], K=M, SK=4; dual-write X = X0
  gemm_nt_sk<<<dim3(cdiv(NBB, 64), cdiv(N, 64), 4), blk, 0, stream>>>(
      y2, d_Q, Pbuf, N, NBB, M, M, M, 4);
  reduce_sk_k<<<cdiv(N * NBB, 256), blk, 0, stream>>>(
      Pbuf, X0, X, (long long)N * NBB, (long long)N * NBB, 4, 0,
      nullptr, nullptr, nullptr);

  for (int n = 0; n < layers; ++n) {
    const float* stepp = d_steps + n;

    // ---- denoise CNN on X (512 images of 33x33); conv4 emits T = X + noise ----
    zero_borders_k<<<cdiv(N * (2 * 35 + 2 * 33), 256), blk, 0, stream>>>(buf1, buf2, N, BLKSZ, BLKSZ);
    conv1_k<<<cdiv(N * NBB, 256), blk, 0, stream>>>(X, buf1, den_w1 + n * 288, den_b1 + n * 32, N, BLKSZ, BLKSZ);
    conv2_mfma_k<<<cdiv(N * 2 * 3 * 3, 4), blk, 0, stream>>>(
        buf1, buf2, wph + (size_t)(n * 4 + 0) * 9216, den_b2 + n * 32, N, BLKSZ, BLKSZ, 11);
    conv2_mfma_k<<<cdiv(N * 2 * 3 * 3, 4), blk, 0, stream>>>(
        buf2, buf1, wph + (size_t)(n * 4 + 1) * 9216, den_b3 + n * 32, N, BLKSZ, BLKSZ, 11);
    conv4_k<<<cdiv(N * NBB, 256), blk, 0, stream>>>(buf1, T, den_w4 + n * 288, X, N, BLKSZ, BLKSZ, 1.f);

    // ---- X = T - step*(T@AtA) + step*X0   (one NT-GEMM, K=1089, SK=8) ----
    gemm_nt_sk<<<dim3(cdiv(NBB, 64), cdiv(N, 64), 8), blk, 0, stream>>>(
        T, AtA, Pbuf, N, NBB, NBB, NBB, NBB, 8);
    reduce_sk_k<<<cdiv(N * NBB, 256), blk, 0, stream>>>(
        Pbuf, X, nullptr, (long long)N * NBB, (long long)N * NBB, 8, 4,
        stepp, T, X0);

    // img = unblockify(X)
    unblockify_k<<<cdiv(S * IMW * IMW, 256), blk, 0, stream>>>(X, img, S);

    // ---- deblock CNN on img (S images of 264x264) ----
    zero_borders_k<<<cdiv(S * (2 * 266 + 2 * 264), 256), blk, 0, stream>>>(buf1, buf2, S, IMW, IMW);
    conv1_k<<<cdiv(S * IMW * IMW, 256), blk, 0, stream>>>(img, buf1, deb_w1 + n * 288, deb_b1 + n * 32, S, IMW, IMW);
    conv2_mfma_k<<<cdiv(S * 2 * 17 * 33, 4), blk, 0, stream>>>(
        buf1, buf2, wph + (size_t)(n * 4 + 2) * 9216, deb_b2 + n * 32, S, IMW, IMW, 8);
    conv2_mfma_k<<<cdiv(S * 2 * 17 * 33, 4), blk, 0, stream>>>(
        buf2, buf1, wph + (size_t)(n * 4 + 3) * 9216, deb_b3 + n * 32, S, IMW, IMW, 8);
    conv4_k<<<cdiv(S * IMW * IMW, 256), blk, 0, stream>>>(buf1, img, deb_w4 + n * 288, img, S, IMW, IMW, -1.f);

    // X = blockify(img)
    blockify_k<<<cdiv(N * NBB, 256), blk, 0, stream>>>(img, X, S);
  }

  // output = unblockify(X)
  unblockify_k<<<cdiv(S * IMW * IMW, 256), blk, 0, stream>>>(X, (float*)d_out, S);
}